// Round 2
// baseline (320.918 us; speedup 1.0000x reference)
//
#include <hip/hip_runtime.h>

// Problem constants (match reference)
#define B_   256
#define M_   16
#define A_   4096
#define NS_  1024
#define T_   64
#define AT_  (A_ + T_)

static constexpr float DTc = 0.001f;
static constexpr float DAc = 0.001f;
static constexpr float LOG_DT = -6.907755278982137f;   // ln(0.001)

// Output layout (flat, concatenated in reference return order)
static constexpr size_t OFF_AT    = 0;                         // A_t   (B*M)
static constexpr size_t OFF_Z     = 4096;                      // Z     (B*M)
static constexpr size_t OFF_ZNLL  = 8192;                      // Z_nll (B*M)
static constexpr size_t OFF_LNPY  = 12288;                     // lnPy  (B*M*NS)
static constexpr size_t OFF_LNP1Y = 12288 + 4194304;           // lnP1_y
static constexpr size_t OFF_VT    = 12288 + 2ull * 4194304;    // V_t_new (B*M*A)
static constexpr size_t OFF_SNV   = OFF_VT + 16777216ull;      // snv_new
static constexpr size_t OFF_ISYN  = OFF_SNV + 4194304ull;      // I_syn (B*M)

// clang native 4-float vector — accepted by __builtin_nontemporal_store
typedef float v4f __attribute__((ext_vector_type(4)));

static __device__ __forceinline__ void nt_store4(float* p, float a, float b, float c, float d) {
    v4f v; v.x = a; v.y = b; v.z = c; v.w = d;
    __builtin_nontemporal_store(v, reinterpret_cast<v4f*>(p));
}

__global__ __launch_bounds__(256, 8) void lif_kernel(
    const float* __restrict__ x,
    const float* __restrict__ V_t_old,
    const float* __restrict__ logS_t_old,
    const float* __restrict__ snv_in,
    const float* __restrict__ snlf,
    const float* __restrict__ I_syn,
    const float* __restrict__ amem,
    const float* __restrict__ asyn,
    const float* __restrict__ J,
    const float* __restrict__ rp,
    const float* __restrict__ ft,
    const float* __restrict__ eps,
    const float* __restrict__ Z_hist,
    const int*   __restrict__ clk_ptr,
    float* __restrict__ out)
{
    const int row = blockIdx.x;      // b*M + m
    const int b   = row >> 4;
    const int m   = row & 15;
    const int tid = threadIdx.x;

    __shared__ float sh_I[M_];
    __shared__ float sh_inT;
    __shared__ float sh_red[4][4];

    const int clk = *clk_ptr;

    // ---- I_syn update (per b, all m') ----
    if (tid < M_) {
        float es   = expf(-DTc * asyn[tid]);
        float Iold = I_syn[b * M_ + tid];
        float In   = Iold;
        if (clk > 1) {  // SYN_DELAY_BINS = 1
            float zl = Z_hist[(size_t)(b * M_ + tid) * AT_ + (clk + A_ - 2)];
            In = es * Iold + (1.0f - es) * zl / DTc;
        }
        sh_I[tid] = In;
    }
    __syncthreads();
    // ---- input_total: 16-lane parallel dot instead of serial on tid 0 ----
    if (tid < M_) {
        float t = sh_I[tid] * J[tid * M_ + m];
#pragma unroll
        for (int off = 8; off > 0; off >>= 1) t += __shfl_down(t, off, 16);
        if (tid == 0) {
            sh_inT = t + x[row] * eps[0];
            out[OFF_ISYN + row] = sh_I[m];
        }
    }
    __syncthreads();

    const float a_m  = amem[m];
    const float rp_m = rp[m];
    const float ft_m = ft[m];
    const float inT  = sh_inT;

    const size_t rowA = (size_t)row * A_;
    const size_t rowZ = (size_t)row * AT_;

    // Reversed Z window: Z_t[a] = Z_hist[rowZ + clk + A - 1 - a].
    // Forward float4 at (clk + A - 4 - a0) then reverse in registers.
    // 16B-aligned iff clk % 4 == 0 (uniform branch otherwise).
    const bool zal = ((clk & 3) == 0);

    const float* pV = V_t_old    + rowA + tid * 4;
    const float* pS = logS_t_old + rowA + tid * 4;
    const float* pZ = Z_hist     + rowZ + (clk + A_ - 4 - tid * 4);

    // ---- software-pipelined main A loop: prefetch chunk c+1 during chunk c ----
    float4 vc = *reinterpret_cast<const float4*>(pV);
    float4 sc = *reinterpret_cast<const float4*>(pS);
    float4 zc = zal ? *reinterpret_cast<const float4*>(pZ)
                    : make_float4(pZ[0], pZ[1], pZ[2], pZ[3]);

    float sZm = 0.0f, sMt = 0.0f, sNum = 0.0f, sDen = 0.0f;

#pragma unroll
    for (int c = 0; c < 4; ++c) {
        float4 vn_, sn_, zn_;
        if (c < 3) {
            const float* qV = pV + (c + 1) * 1024;
            const float* qS = pS + (c + 1) * 1024;
            const float* qZ = pZ - (c + 1) * 1024;
            vn_ = *reinterpret_cast<const float4*>(qV);
            sn_ = *reinterpret_cast<const float4*>(qS);
            zn_ = zal ? *reinterpret_cast<const float4*>(qZ)
                      : make_float4(qZ[0], qZ[1], qZ[2], qZ[3]);
        }

        const int a0 = c * 1024 + tid * 4;
        const float vov[4]  = {vc.x, vc.y, vc.z, vc.w};
        const float lsv[4]  = {sc.x, sc.y, sc.z, sc.w};
        const float zrev[4] = {zc.w, zc.z, zc.y, zc.x};  // z(k) = fwd[3-k]
        float vres[4];
#pragma unroll
        for (int k = 0; k < 4; ++k) {
            const int a = a0 + k;
            float V = vov[k] + DAc * (rp_m - vov[k]) * a_m + DAc * inT;
            if (a < 4) V = 0.0f;                       // age < REF_T (a*DA < 0.004)
            float lam  = (V == 0.0f) ? 1e-8f : expf(V - ft_m);
            float p    = lam * DTc;
            float Plam = (p >= 0.01f) ? (1.0f - expf(-p)) : p;
            float S    = expf(lsv[k]);
            float mt   = S * zrev[k];
            sZm += mt * Plam;
            sMt += mt;
            float v = (1.0f - S) * mt;
            sNum += v * Plam;
            sDen += v;
            vres[k] = V;
        }
        nt_store4(out + OFF_VT + rowA + a0, vres[0], vres[1], vres[2], vres[3]);
        vc = vn_; sc = sn_; zc = zn_;
    }

    // ---- issue sampled-neuron loads now; latency hides under reduction/epilogue ----
    const size_t rowS = (size_t)row * NS_;
    const int s0 = tid * 4;
    const float4 v4  = *reinterpret_cast<const float4*>(snv_in + rowS + s0);
    const float4 lf4 = *reinterpret_cast<const float4*>(snlf   + rowS + s0);

    // ---- block reduction of the 4 sums ----
    float vals[4] = {sZm, sMt, sNum, sDen};
#pragma unroll
    for (int i = 0; i < 4; ++i) {
        float v = vals[i];
        for (int off = 32; off > 0; off >>= 1) v += __shfl_down(v, off, 64);
        vals[i] = v;
    }
    const int wave = tid >> 6, lane = tid & 63;
    if (lane == 0) {
#pragma unroll
        for (int i = 0; i < 4; ++i) sh_red[wave][i] = vals[i];
    }
    __syncthreads();
    if (tid == 0) {
        float Zm  = sh_red[0][0] + sh_red[1][0] + sh_red[2][0] + sh_red[3][0];
        float sM  = sh_red[0][1] + sh_red[1][1] + sh_red[2][1] + sh_red[3][1];
        float num = sh_red[0][2] + sh_red[1][2] + sh_red[2][2] + sh_red[3][2];
        float den = sh_red[0][3] + sh_red[1][3] + sh_red[2][3] + sh_red[3][3];
        float mess  = 1.0f - sM;
        float lam_t = (den != 0.0f) ? (num / den) : 0.0f;
        float Z = Zm + lam_t * mess;
        Z = fminf(fmaxf(Z, 0.0f), 1.0f);
        float At  = Z / DTc;
        float var = Z / 500.0f + 0.1f * DTc / 500.0f;
        float ztn = Z_hist[rowZ + clk + A_];
        float d   = ztn - Z;
        float znll = 0.5f * (d * d) / var + 0.5f * logf(var) + 0.5f * logf(2.0f * 3.14f);
        out[OFF_AT   + row] = At;
        out[OFF_Z    + row] = Z;
        out[OFF_ZNLL + row] = znll;
    }

    // ---- sampled-neuron compute (loads already in flight) ----
    {
        const float vv[4] = {v4.x, v4.y, v4.z, v4.w};
        const float lf[4] = {lf4.x, lf4.y, lf4.z, lf4.w};
        float vn[4], py[4], p1[4];
#pragma unroll
        for (int k = 0; k < 4; ++k) {
            float V = vv[k] + DAc * (rp_m - vv[k]) * a_m + DAc * inT;
            if (lf[k] < 0.004f) V = 0.0f;              // age < REF_T
            float lam  = (V == 0.0f) ? 1e-8f : expf(V - ft_m);
            float ltdt = lam * DTc;
            float Plam = (ltdt >= 0.01f) ? (1.0f - expf(-ltdt)) : ltdt;
            py[k] = (ltdt < 0.01f) ? (V - ft_m + LOG_DT) : logf(Plam);
            p1[k] = -ltdt;
            vn[k] = V;
        }
        nt_store4(out + OFF_SNV   + rowS + s0, vn[0], vn[1], vn[2], vn[3]);
        nt_store4(out + OFF_LNPY  + rowS + s0, py[0], py[1], py[2], py[3]);
        nt_store4(out + OFF_LNP1Y + rowS + s0, p1[0], p1[1], p1[2], p1[3]);
    }
}

extern "C" void kernel_launch(void* const* d_in, const int* in_sizes, int n_in,
                              void* d_out, int out_size, void* d_ws, size_t ws_size,
                              hipStream_t stream) {
    lif_kernel<<<B_ * M_, 256, 0, stream>>>(
        (const float*)d_in[0],   // x
        (const float*)d_in[1],   // V_t_old
        (const float*)d_in[2],   // logS_t_old
        (const float*)d_in[3],   // sampled_neuron_v
        (const float*)d_in[4],   // sampled_neuron_lastfire
        (const float*)d_in[5],   // I_syn
        (const float*)d_in[6],   // amem
        (const float*)d_in[7],   // asyn
        (const float*)d_in[8],   // J
        (const float*)d_in[9],   // rp
        (const float*)d_in[10],  // ft
        (const float*)d_in[11],  // eps
        (const float*)d_in[12],  // Z_hist_est
        (const int*)  d_in[13],  // internal_clock
        (float*)d_out);
}

// Round 3
// 307.374 us; speedup vs baseline: 1.0441x; 1.0441x over previous
//
#include <hip/hip_runtime.h>

// Problem constants (match reference)
#define B_   256
#define M_   16
#define A_   4096
#define NS_  1024
#define T_   64
#define AT_  (A_ + T_)

static constexpr float DTc = 0.001f;
static constexpr float DAc = 0.001f;
static constexpr float LOG_DT = -6.907755278982137f;   // ln(0.001)

// Output layout (flat, concatenated in reference return order)
static constexpr size_t OFF_AT    = 0;                         // A_t   (B*M)
static constexpr size_t OFF_Z     = 4096;                      // Z     (B*M)
static constexpr size_t OFF_ZNLL  = 8192;                      // Z_nll (B*M)
static constexpr size_t OFF_LNPY  = 12288;                     // lnPy  (B*M*NS)
static constexpr size_t OFF_LNP1Y = 12288 + 4194304;           // lnP1_y
static constexpr size_t OFF_VT    = 12288 + 2ull * 4194304;    // V_t_new (B*M*A)
static constexpr size_t OFF_SNV   = OFF_VT + 16777216ull;      // snv_new
static constexpr size_t OFF_ISYN  = OFF_SNV + 4194304ull;      // I_syn (B*M)

static __device__ __forceinline__ float4 ld4(const float* p) {
    return *reinterpret_cast<const float4*>(p);
}

// launch_bounds(256, 4): 4 waves/EU min -> 128 VGPR budget, enough to hold
// all 14 preloaded float4s in flight (deep MLP; ILP replaces TLP).
__global__ __launch_bounds__(256, 4) void lif_kernel(
    const float* __restrict__ x,
    const float* __restrict__ V_t_old,
    const float* __restrict__ logS_t_old,
    const float* __restrict__ snv_in,
    const float* __restrict__ snlf,
    const float* __restrict__ I_syn,
    const float* __restrict__ amem,
    const float* __restrict__ asyn,
    const float* __restrict__ J,
    const float* __restrict__ rp,
    const float* __restrict__ ft,
    const float* __restrict__ eps,
    const float* __restrict__ Z_hist,
    const int*   __restrict__ clk_ptr,
    float* __restrict__ out)
{
    const int row  = blockIdx.x;      // b*M + m
    const int b    = row >> 4;
    const int m    = row & 15;
    const int tid  = threadIdx.x;
    const int lane = tid & 63;

    __shared__ float sh_red[4][4];

    const size_t rowA = (size_t)row * A_;
    const size_t rowS = (size_t)row * NS_;

    // ---- uniform scalar loads (s_load path, lgkmcnt — independent of vmcnt) ----
    const int   clk  = *clk_ptr;
    const float xv   = x[row];
    const float ev   = eps[0];
    const float a_m  = amem[m];
    const float rp_m = rp[m];
    const float ft_m = ft[m];

    const size_t rowZ = (size_t)row * AT_;
    const float  ztn  = Z_hist[rowZ + clk + A_];   // uniform, needed only in epilogue

    // ---- prologue small vector loads FIRST (so waiting on them doesn't
    //      require draining the 14 big loads issued after them) ----
    float asy = 0.0f, Iold = 0.0f, Jv = 0.0f, zl = 0.0f;
    if (lane < M_) {
        asy  = asyn[lane];
        Iold = I_syn[b * M_ + lane];
        Jv   = J[lane * M_ + m];
        if (clk > 1) zl = Z_hist[(size_t)(b * M_ + lane) * AT_ + (clk + A_ - 2)];
    }
    __builtin_amdgcn_sched_barrier(0);   // prologue loads stay above big loads

    // ---- big loads: all 14 float4s issued up front ----
    const float* pV = V_t_old    + rowA + tid * 4;
    const float* pS = logS_t_old + rowA + tid * 4;
    const float4 vA = ld4(pV);          const float4 vB = ld4(pV + 1024);
    const float4 vC = ld4(pV + 2048);   const float4 vD = ld4(pV + 3072);
    const float4 sA = ld4(pS);          const float4 sB = ld4(pS + 1024);
    const float4 sC = ld4(pS + 2048);   const float4 sD = ld4(pS + 3072);
    const float4 n4  = ld4(snv_in + rowS + tid * 4);
    const float4 lf4 = ld4(snlf   + rowS + tid * 4);

    // Reversed Z window: Z_t[a] = Z_hist[rowZ + clk + A - 1 - a];
    // forward float4 then reverse in registers. Aligned iff clk % 4 == 0.
    const bool  zal = ((clk & 3) == 0);
    const float* pZ = Z_hist + rowZ + (clk + A_ - 4 - tid * 4);
    float4 zA, zB, zC, zD;
    if (zal) {
        zA = ld4(pZ);          zB = ld4(pZ - 1024);
        zC = ld4(pZ - 2048);   zD = ld4(pZ - 3072);
    } else {
        zA = make_float4(pZ[0], pZ[1], pZ[2], pZ[3]);
        zB = make_float4(pZ[-1024], pZ[-1023], pZ[-1022], pZ[-1021]);
        zC = make_float4(pZ[-2048], pZ[-2047], pZ[-2046], pZ[-2045]);
        zD = make_float4(pZ[-3072], pZ[-3071], pZ[-3070], pZ[-3069]);
    }
    __builtin_amdgcn_sched_barrier(0);   // big loads pinned above all compute

    // ---- per-wave redundant prologue: no __syncthreads on the critical path ----
    float In = Iold;
    if (clk > 1 && lane < M_) {          // SYN_DELAY_BINS = 1
        const float es = expf(-DTc * asy);
        In = es * Iold + (1.0f - es) * zl / DTc;
    }
    if (tid == m) out[OFF_ISYN + row] = In;   // wave-0 lane m holds I_syn_new[b,m]
    float t = (lane < M_) ? In * Jv : 0.0f;
#pragma unroll
    for (int off = 8; off > 0; off >>= 1) t += __shfl_xor(t, off, 16);
    const float inT = __shfl(t, 0, 64) + xv * ev;

    // ---- main A compute: 4 chunks, all data already in registers ----
    float sZm = 0.0f, sMt = 0.0f, sNum = 0.0f, sDen = 0.0f;

#define CHUNK(cidx, vc, sc, zc)                                                 \
    do {                                                                        \
        const int a0 = (cidx) * 1024 + tid * 4;                                 \
        const float vov[4]  = {vc.x, vc.y, vc.z, vc.w};                         \
        const float lsv[4]  = {sc.x, sc.y, sc.z, sc.w};                         \
        const float zrev[4] = {zc.w, zc.z, zc.y, zc.x};                         \
        float vres[4];                                                          \
        _Pragma("unroll")                                                       \
        for (int k = 0; k < 4; ++k) {                                           \
            const int a = a0 + k;                                               \
            float V = vov[k] + DAc * (rp_m - vov[k]) * a_m + DAc * inT;         \
            if (a < 4) V = 0.0f;                    /* age < REF_T */           \
            float lam  = (V == 0.0f) ? 1e-8f : expf(V - ft_m);                  \
            float p    = lam * DTc;                                             \
            float Plam = (p >= 0.01f) ? (1.0f - expf(-p)) : p;                  \
            float S    = expf(lsv[k]);                                          \
            float mt   = S * zrev[k];                                           \
            sZm += mt * Plam;                                                   \
            sMt += mt;                                                          \
            float v = (1.0f - S) * mt;                                          \
            sNum += v * Plam;                                                   \
            sDen += v;                                                          \
            vres[k] = V;                                                        \
        }                                                                       \
        *reinterpret_cast<float4*>(out + OFF_VT + rowA + a0) =                  \
            make_float4(vres[0], vres[1], vres[2], vres[3]);                    \
    } while (0)

    CHUNK(0, vA, sA, zA);
    CHUNK(1, vB, sB, zB);
    CHUNK(2, vC, sC, zC);
    CHUNK(3, vD, sD, zD);
#undef CHUNK

    // ---- sampled-neuron compute (data preloaded) ----
    {
        const float vv[4] = {n4.x, n4.y, n4.z, n4.w};
        const float lf[4] = {lf4.x, lf4.y, lf4.z, lf4.w};
        float vn[4], py[4], p1[4];
#pragma unroll
        for (int k = 0; k < 4; ++k) {
            float V = vv[k] + DAc * (rp_m - vv[k]) * a_m + DAc * inT;
            if (lf[k] < 0.004f) V = 0.0f;              // age < REF_T
            float lam  = (V == 0.0f) ? 1e-8f : expf(V - ft_m);
            float ltdt = lam * DTc;
            float Plam = (ltdt >= 0.01f) ? (1.0f - expf(-ltdt)) : ltdt;
            py[k] = (ltdt < 0.01f) ? (V - ft_m + LOG_DT) : logf(Plam);
            p1[k] = -ltdt;
            vn[k] = V;
        }
        const int s0 = tid * 4;
        *reinterpret_cast<float4*>(out + OFF_SNV   + rowS + s0) = make_float4(vn[0], vn[1], vn[2], vn[3]);
        *reinterpret_cast<float4*>(out + OFF_LNPY  + rowS + s0) = make_float4(py[0], py[1], py[2], py[3]);
        *reinterpret_cast<float4*>(out + OFF_LNP1Y + rowS + s0) = make_float4(p1[0], p1[1], p1[2], p1[3]);
    }

    // ---- block reduction of the 4 sums (single barrier in the kernel) ----
    float vals[4] = {sZm, sMt, sNum, sDen};
#pragma unroll
    for (int i = 0; i < 4; ++i) {
        float v = vals[i];
        for (int off = 32; off > 0; off >>= 1) v += __shfl_down(v, off, 64);
        vals[i] = v;
    }
    const int wave = tid >> 6;
    if (lane == 0) {
#pragma unroll
        for (int i = 0; i < 4; ++i) sh_red[wave][i] = vals[i];
    }
    __syncthreads();
    if (tid == 0) {
        float Zm  = sh_red[0][0] + sh_red[1][0] + sh_red[2][0] + sh_red[3][0];
        float sM  = sh_red[0][1] + sh_red[1][1] + sh_red[2][1] + sh_red[3][1];
        float num = sh_red[0][2] + sh_red[1][2] + sh_red[2][2] + sh_red[3][2];
        float den = sh_red[0][3] + sh_red[1][3] + sh_red[2][3] + sh_red[3][3];
        float mess  = 1.0f - sM;
        float lam_t = (den != 0.0f) ? (num / den) : 0.0f;
        float Z = Zm + lam_t * mess;
        Z = fminf(fmaxf(Z, 0.0f), 1.0f);
        float At  = Z / DTc;
        float var = Z / 500.0f + 0.1f * DTc / 500.0f;
        float d   = ztn - Z;
        float znll = 0.5f * (d * d) / var + 0.5f * logf(var) + 0.5f * logf(2.0f * 3.14f);
        out[OFF_AT   + row] = At;
        out[OFF_Z    + row] = Z;
        out[OFF_ZNLL + row] = znll;
    }
}

extern "C" void kernel_launch(void* const* d_in, const int* in_sizes, int n_in,
                              void* d_out, int out_size, void* d_ws, size_t ws_size,
                              hipStream_t stream) {
    lif_kernel<<<B_ * M_, 256, 0, stream>>>(
        (const float*)d_in[0],   // x
        (const float*)d_in[1],   // V_t_old
        (const float*)d_in[2],   // logS_t_old
        (const float*)d_in[3],   // sampled_neuron_v
        (const float*)d_in[4],   // sampled_neuron_lastfire
        (const float*)d_in[5],   // I_syn
        (const float*)d_in[6],   // amem
        (const float*)d_in[7],   // asyn
        (const float*)d_in[8],   // J
        (const float*)d_in[9],   // rp
        (const float*)d_in[10],  // ft
        (const float*)d_in[11],  // eps
        (const float*)d_in[12],  // Z_hist_est
        (const int*)  d_in[13],  // internal_clock
        (float*)d_out);
}

// Round 4
// 306.494 us; speedup vs baseline: 1.0471x; 1.0029x over previous
//
#include <hip/hip_runtime.h>

// Problem constants (match reference)
#define B_   256
#define M_   16
#define A_   4096
#define NS_  1024
#define T_   64
#define AT_  (A_ + T_)

static constexpr float DTc = 0.001f;
static constexpr float DAc = 0.001f;
static constexpr float LOG_DT = -6.907755278982137f;   // ln(0.001)

// Output layout (flat, concatenated in reference return order)
static constexpr size_t OFF_AT    = 0;                         // A_t   (B*M)
static constexpr size_t OFF_Z     = 4096;                      // Z     (B*M)
static constexpr size_t OFF_ZNLL  = 8192;                      // Z_nll (B*M)
static constexpr size_t OFF_LNPY  = 12288;                     // lnPy  (B*M*NS)
static constexpr size_t OFF_LNP1Y = 12288 + 4194304;           // lnP1_y
static constexpr size_t OFF_VT    = 12288 + 2ull * 4194304;    // V_t_new (B*M*A)
static constexpr size_t OFF_SNV   = OFF_VT + 16777216ull;      // snv_new
static constexpr size_t OFF_ISYN  = OFF_SNV + 4194304ull;      // I_syn (B*M)

// clang native vector: binds to a 4-VGPR tuple under the "v" asm constraint
typedef float v4f __attribute__((ext_vector_type(4)));

static __device__ __forceinline__ v4f ldv(const float* p) {
    return *reinterpret_cast<const v4f*>(p);
}

// launch_bounds(256,4): min 4 waves/EU -> 128-VGPR budget for the 14-vector burst.
__global__ __launch_bounds__(256, 4) void lif_kernel(
    const float* __restrict__ x,
    const float* __restrict__ V_t_old,
    const float* __restrict__ logS_t_old,
    const float* __restrict__ snv_in,
    const float* __restrict__ snlf,
    const float* __restrict__ I_syn,
    const float* __restrict__ amem,
    const float* __restrict__ asyn,
    const float* __restrict__ J,
    const float* __restrict__ rp,
    const float* __restrict__ ft,
    const float* __restrict__ eps,
    const float* __restrict__ Z_hist,
    const int*   __restrict__ clk_ptr,
    float* __restrict__ out)
{
    const int row  = blockIdx.x;      // b*M + m
    const int b    = row >> 4;
    const int m    = row & 15;
    const int tid  = threadIdx.x;
    const int lane = tid & 63;

    __shared__ float sh_red[4][4];

    const size_t rowA = (size_t)row * A_;
    const size_t rowS = (size_t)row * NS_;
    const size_t rowZ = (size_t)row * AT_;

    // ---- uniform scalar loads (SMEM path, lgkmcnt — independent of vmcnt) ----
    const int   clk  = *clk_ptr;
    const float xv   = x[row];
    const float ev   = eps[0];
    const float a_m  = amem[m];
    const float rp_m = rp[m];
    const float ft_m = ft[m];
    const float ztn  = Z_hist[rowZ + clk + A_];   // uniform, epilogue only

    // ---- prologue lane loads (needed for inT, computed during big-load flight) ----
    float asy = 0.0f, Iold = 0.0f, Jv = 0.0f, zl = 0.0f;
    if (lane < M_) {
        asy  = asyn[lane];
        Iold = I_syn[b * M_ + lane];
        Jv   = J[lane * M_ + m];
        if (clk > 1) zl = Z_hist[(size_t)(b * M_ + lane) * AT_ + (clk + A_ - 2)];
    }

    // ---- 14-vector burst: issue everything, pin with a register keepalive ----
    const float* pV = V_t_old    + rowA + tid * 4;
    const float* pS = logS_t_old + rowA + tid * 4;
    const float* pZ = Z_hist + rowZ + (clk + A_ - 4 - tid * 4);  // reversed window
    const bool   zal = ((clk & 3) == 0);

    v4f vA = ldv(pV);          v4f vB = ldv(pV + 1024);
    v4f vC = ldv(pV + 2048);   v4f vD = ldv(pV + 3072);
    v4f sA = ldv(pS);          v4f sB = ldv(pS + 1024);
    v4f sC = ldv(pS + 2048);   v4f sD = ldv(pS + 3072);
    v4f zA, zB, zC, zD;
    if (zal) {
        zA = ldv(pZ);          zB = ldv(pZ - 1024);
        zC = ldv(pZ - 2048);   zD = ldv(pZ - 3072);
    } else {
        zA.x = pZ[0];     zA.y = pZ[1];     zA.z = pZ[2];     zA.w = pZ[3];
        zB.x = pZ[-1024]; zB.y = pZ[-1023]; zB.z = pZ[-1022]; zB.w = pZ[-1021];
        zC.x = pZ[-2048]; zC.y = pZ[-2047]; zC.z = pZ[-2046]; zC.w = pZ[-2045];
        zD.x = pZ[-3072]; zD.y = pZ[-3071]; zD.z = pZ[-3070]; zD.w = pZ[-3069];
    }
    v4f n4  = ldv(snv_in + rowS + tid * 4);
    v4f lf4 = ldv(snlf   + rowS + tid * 4);

    // ---- inT: per-wave redundant, overlaps big-load flight (no barrier) ----
    float In = Iold;
    if (clk > 1 && lane < M_) {          // SYN_DELAY_BINS = 1
        const float es = expf(-DTc * asy);
        In = es * Iold + (1.0f - es) * zl / DTc;
    }
    if (tid == m) out[OFF_ISYN + row] = In;
    float t = (lane < M_) ? In * Jv : 0.0f;
#pragma unroll
    for (int off = 8; off > 0; off >>= 1) t += __shfl_xor(t, off, 16);
    const float inT = __shfl(t, 0, 64) + xv * ev;

    // Keepalive: asm READS all 14 vectors (forces loads issued above + one
    // vmcnt drain here) and REDEFINES them (forbids sinking/remat after).
    asm volatile("" : "+v"(vA), "+v"(vB), "+v"(vC), "+v"(vD),
                      "+v"(sA), "+v"(sB), "+v"(sC), "+v"(sD),
                      "+v"(zA), "+v"(zB), "+v"(zC), "+v"(zD),
                      "+v"(n4), "+v"(lf4));

    // ---- main A compute: 4 chunks, all data in registers ----
    float sZm = 0.0f, sMt = 0.0f, sNum = 0.0f, sDen = 0.0f;

#define CHUNK(cidx, vc, sc, zc)                                                 \
    do {                                                                        \
        const int a0 = (cidx) * 1024 + tid * 4;                                 \
        const float vov[4]  = {vc.x, vc.y, vc.z, vc.w};                         \
        const float lsv[4]  = {sc.x, sc.y, sc.z, sc.w};                         \
        const float zrev[4] = {zc.w, zc.z, zc.y, zc.x};                         \
        float vres[4];                                                          \
        _Pragma("unroll")                                                       \
        for (int k = 0; k < 4; ++k) {                                           \
            const int a = a0 + k;                                               \
            float V = vov[k] + DAc * (rp_m - vov[k]) * a_m + DAc * inT;         \
            if (a < 4) V = 0.0f;                    /* age < REF_T */           \
            float lam  = (V == 0.0f) ? 1e-8f : expf(V - ft_m);                  \
            float p    = lam * DTc;                                             \
            float Plam = (p >= 0.01f) ? (1.0f - expf(-p)) : p;                  \
            float S    = expf(lsv[k]);                                          \
            float mt   = S * zrev[k];                                           \
            sZm += mt * Plam;                                                   \
            sMt += mt;                                                          \
            float v = (1.0f - S) * mt;                                          \
            sNum += v * Plam;                                                   \
            sDen += v;                                                          \
            vres[k] = V;                                                        \
        }                                                                       \
        v4f vo; vo.x = vres[0]; vo.y = vres[1]; vo.z = vres[2]; vo.w = vres[3]; \
        *reinterpret_cast<v4f*>(out + OFF_VT + rowA + a0) = vo;                 \
    } while (0)

    CHUNK(0, vA, sA, zA);
    CHUNK(1, vB, sB, zB);
    CHUNK(2, vC, sC, zC);
    CHUNK(3, vD, sD, zD);
#undef CHUNK

    // ---- sampled-neuron compute (data already in registers) ----
    {
        const float vv[4] = {n4.x, n4.y, n4.z, n4.w};
        const float lf[4] = {lf4.x, lf4.y, lf4.z, lf4.w};
        float vn[4], py[4], p1[4];
#pragma unroll
        for (int k = 0; k < 4; ++k) {
            float V = vv[k] + DAc * (rp_m - vv[k]) * a_m + DAc * inT;
            if (lf[k] < 0.004f) V = 0.0f;              // age < REF_T
            float lam  = (V == 0.0f) ? 1e-8f : expf(V - ft_m);
            float ltdt = lam * DTc;
            float Plam = (ltdt >= 0.01f) ? (1.0f - expf(-ltdt)) : ltdt;
            py[k] = (ltdt < 0.01f) ? (V - ft_m + LOG_DT) : logf(Plam);
            p1[k] = -ltdt;
            vn[k] = V;
        }
        const int s0 = tid * 4;
        v4f o0; o0.x = vn[0]; o0.y = vn[1]; o0.z = vn[2]; o0.w = vn[3];
        v4f o1; o1.x = py[0]; o1.y = py[1]; o1.z = py[2]; o1.w = py[3];
        v4f o2; o2.x = p1[0]; o2.y = p1[1]; o2.z = p1[2]; o2.w = p1[3];
        *reinterpret_cast<v4f*>(out + OFF_SNV   + rowS + s0) = o0;
        *reinterpret_cast<v4f*>(out + OFF_LNPY  + rowS + s0) = o1;
        *reinterpret_cast<v4f*>(out + OFF_LNP1Y + rowS + s0) = o2;
    }

    // ---- block reduction of the 4 sums (single barrier in the kernel) ----
    float vals[4] = {sZm, sMt, sNum, sDen};
#pragma unroll
    for (int i = 0; i < 4; ++i) {
        float v = vals[i];
        for (int off = 32; off > 0; off >>= 1) v += __shfl_down(v, off, 64);
        vals[i] = v;
    }
    const int wave = tid >> 6;
    if (lane == 0) {
#pragma unroll
        for (int i = 0; i < 4; ++i) sh_red[wave][i] = vals[i];
    }
    __syncthreads();
    if (tid == 0) {
        float Zm  = sh_red[0][0] + sh_red[1][0] + sh_red[2][0] + sh_red[3][0];
        float sM  = sh_red[0][1] + sh_red[1][1] + sh_red[2][1] + sh_red[3][1];
        float num = sh_red[0][2] + sh_red[1][2] + sh_red[2][2] + sh_red[3][2];
        float den = sh_red[0][3] + sh_red[1][3] + sh_red[2][3] + sh_red[3][3];
        float mess  = 1.0f - sM;
        float lam_t = (den != 0.0f) ? (num / den) : 0.0f;
        float Z = Zm + lam_t * mess;
        Z = fminf(fmaxf(Z, 0.0f), 1.0f);
        float At  = Z / DTc;
        float var = Z / 500.0f + 0.1f * DTc / 500.0f;
        float d   = ztn - Z;
        float znll = 0.5f * (d * d) / var + 0.5f * logf(var) + 0.5f * logf(2.0f * 3.14f);
        out[OFF_AT   + row] = At;
        out[OFF_Z    + row] = Z;
        out[OFF_ZNLL + row] = znll;
    }
}

extern "C" void kernel_launch(void* const* d_in, const int* in_sizes, int n_in,
                              void* d_out, int out_size, void* d_ws, size_t ws_size,
                              hipStream_t stream) {
    lif_kernel<<<B_ * M_, 256, 0, stream>>>(
        (const float*)d_in[0],   // x
        (const float*)d_in[1],   // V_t_old
        (const float*)d_in[2],   // logS_t_old
        (const float*)d_in[3],   // sampled_neuron_v
        (const float*)d_in[4],   // sampled_neuron_lastfire
        (const float*)d_in[5],   // I_syn
        (const float*)d_in[6],   // amem
        (const float*)d_in[7],   // asyn
        (const float*)d_in[8],   // J
        (const float*)d_in[9],   // rp
        (const float*)d_in[10],  // ft
        (const float*)d_in[11],  // eps
        (const float*)d_in[12],  // Z_hist_est
        (const int*)  d_in[13],  // internal_clock
        (float*)d_out);
}